// Round 1
// baseline (6561.669 us; speedup 1.0000x reference)
//
#include <hip/hip_runtime.h>

// ---------------------------------------------------------------------------
// 3-layer SimpleRNN, B=256 T=512 U=512 E=128, fp16 MFMA, pipelined across
// layers with flag-based producer/consumer sync (no grid barriers).
//
// Decomposition: 96 blocks = layer(3) x batch-group(8, 32 rows) x N-strip(4, 128 cols).
// Each wave (4/block) owns a 32-col strip of Wh (and Wx) as register-resident
// MFMA B-fragments (~256 VGPRs) -> zero weight re-streaming per step.
// h state ring-buffered (depth 4) in global ws; staged to LDS (swizzled) as
// MFMA A-fragments each step. Device-scope acquire/release atomics for
// cross-block (cross-XCD-safe) ordering.
// ---------------------------------------------------------------------------

#define BATCH 256
#define SEQ   512
#define EMBD  128
#define UNIT  512

typedef _Float16 half8 __attribute__((ext_vector_type(8)));
typedef _Float16 half4 __attribute__((ext_vector_type(4)));
typedef float    f32x4 __attribute__((ext_vector_type(4)));
typedef unsigned int uint4v __attribute__((ext_vector_type(4)));

// ws layout (bytes). Total ~4.63 MB.
#define FLAGS_BYTES 4096
#define HBUF_OFF    4096
#define HBUF_ELEMS  (3*8*4*32*512)          // [layer][mgroup][slot][32][512] f16
#define HBUF_BYTES  (HBUF_ELEMS*2)
#define PWX0_OFF    (HBUF_OFF + HBUF_BYTES)
#define PWH0_OFF    (PWX0_OFF + EMBD*UNIT*2)
#define PWX1_OFF    (PWH0_OFF + UNIT*UNIT*2)
#define PWH1_OFF    (PWX1_OFF + UNIT*UNIT*2)

// ---------------------------------------------------------------------------
__global__ void zero_ws_kernel(uint4v* __restrict__ p, int n16) {
    int i = blockIdx.x * 256 + threadIdx.x;
    uint4v z = {0u, 0u, 0u, 0u};
    if (i < n16) p[i] = z;
}

// Pack fp32 weight [K][N] into MFMA B-fragment order, fp16:
// dst[((nt*KT + kt)*64 + lane)*8 + j] = W[kt*32 + (lane>>4)*8 + j][nt*16 + (lane&15)]
__global__ void pack_w_kernel(const float* __restrict__ src, _Float16* __restrict__ dst,
                              int K, int N) {
    int idx = blockIdx.x * 256 + threadIdx.x;
    if (idx >= K * N) return;
    int j    = idx & 7;
    int lane = (idx >> 3) & 63;
    int rest = idx >> 9;
    int KT   = K >> 5;
    int kt   = rest % KT;
    int nt   = rest / KT;
    int k = kt*32 + (lane >> 4)*8 + j;
    int n = nt*16 + (lane & 15);
    dst[idx] = (_Float16)src[k * N + n];
}

// ---------------------------------------------------------------------------
__global__ __launch_bounds__(256, 1)
void rnn_main_kernel(const int*   __restrict__ tokens,
                     const float* __restrict__ emb,
                     const float* __restrict__ b0,
                     const float* __restrict__ b1,
                     char* ws)
{
    const int bid   = blockIdx.x;
    const int layer = bid >> 5;          // 0..2
    const int mg    = (bid >> 2) & 7;    // batch group (32 rows)
    const int ns    = bid & 3;           // N-strip (128 cols)
    const int tid   = threadIdx.x;
    const int wv    = tid >> 6;
    const int lane  = tid & 63;
    const int q     = lane >> 4;         // quad
    const int c16   = lane & 15;

    int* flags   = (int*)ws;
    int* flagOwn = flags + layer*8 + mg;

    _Float16* hbuf = (_Float16*)(ws + HBUF_OFF);
    const _Float16* pWh = (const _Float16*)(ws + (layer == 0 ? PWH0_OFF : PWH1_OFF));
    const _Float16* pWx = (const _Float16*)(ws + (layer == 0 ? PWX0_OFF : PWX1_OFF));
    const float* bias = (layer == 0) ? b0 : b1;

    const int c0  = ns*128 + wv*32;      // global col base of this wave
    const int nt0 = c0 >> 4;

    // LDS: exactly 64KB. Rows swizzled by 16B-chunk rotation (chunk' = (chunk+row)&63)
    __shared__ _Float16 Ah [32][512];
    __shared__ _Float16 Ain[32][512];

    // ---- register-resident weights (B-fragments) ----
    half8 whf[16][2];
    half8 wxf[16][2];
#pragma unroll
    for (int kt = 0; kt < 16; ++kt)
#pragma unroll
        for (int n = 0; n < 2; ++n)
            whf[kt][n] = *(const half8*)&pWh[(((nt0 + n)*16 + kt)*64 + lane) * 8];
    if (layer == 0) {
#pragma unroll
        for (int kt = 0; kt < 4; ++kt)
#pragma unroll
            for (int n = 0; n < 2; ++n)
                wxf[kt][n] = *(const half8*)&pWx[(((nt0 + n)*4 + kt)*64 + lane) * 8];
    } else {
#pragma unroll
        for (int kt = 0; kt < 16; ++kt)
#pragma unroll
            for (int n = 0; n < 2; ++n)
                wxf[kt][n] = *(const half8*)&pWx[(((nt0 + n)*16 + kt)*64 + lane) * 8];
    }

    const float bv0 = bias[c0 + c16];
    const float bv1 = bias[c0 + 16 + c16];

    const int m0       = mg * 32;
    const int slotBase = (layer*8 + mg) * 4;

    for (int t = 0; t < SEQ; ++t) {
        // ---- wait: own layer (all 4 strips) finished step t-1 ----
        if (tid == 0) {
            while (__hip_atomic_load(flagOwn, __ATOMIC_ACQUIRE, __HIP_MEMORY_SCOPE_AGENT) < 4*t)
                __builtin_amdgcn_s_sleep(2);
        }
        __syncthreads();

        // ---- stage h_l(t-1) -> Ah (swizzled) ----
        {
            const uint4v* src = (const uint4v*)(hbuf + (slotBase + ((t + 3) & 3)) * 16384);
#pragma unroll
            for (int i = 0; i < 8; ++i) {
                int ci = i*256 + tid;            // 2048 16B-chunks
                int r  = ci >> 6;
                int cc = ci & 63;
                *(uint4v*)&Ah[r][((cc + r) & 63) * 8] = src[ci];
            }
        }
        if (layer == 0) {
            // stage x_t = fp16(emb[tokens[:, t]]) -> Ain cols 0..127 (swizzled)
#pragma unroll
            for (int i = 0; i < 4; ++i) {
                int idx = i*256 + tid;           // 1024 float4 chunks (32 rows x 32)
                int r   = idx >> 5;
                int qq  = idx & 31;
                int tok = tokens[(m0 + r)*SEQ + t];
                float4 f = *((const float4*)(emb + (long)tok * EMBD) + qq);
                half4 h = { (_Float16)f.x, (_Float16)f.y, (_Float16)f.z, (_Float16)f.w };
                *(half4*)&Ain[r][((((qq >> 1) + r) & 63) * 8) + (qq & 1) * 4] = h;
            }
        }
        __syncthreads();

        f32x4 acc00 = {0,0,0,0}, acc01 = {0,0,0,0}, acc10 = {0,0,0,0}, acc11 = {0,0,0,0};

        // ---- Wh GEMM: h_l(t-1) @ Wh[:, strip] ----
#pragma unroll
        for (int kt = 0; kt < 16; ++kt) {
            half8 a0 = *(const half8*)&Ah[c16]     [((kt*4 + q + c16)      & 63) * 8];
            half8 a1 = *(const half8*)&Ah[16 + c16][((kt*4 + q + 16 + c16) & 63) * 8];
            acc00 = __builtin_amdgcn_mfma_f32_16x16x32_f16(a0, whf[kt][0], acc00, 0, 0, 0);
            acc01 = __builtin_amdgcn_mfma_f32_16x16x32_f16(a0, whf[kt][1], acc01, 0, 0, 0);
            acc10 = __builtin_amdgcn_mfma_f32_16x16x32_f16(a1, whf[kt][0], acc10, 0, 0, 0);
            acc11 = __builtin_amdgcn_mfma_f32_16x16x32_f16(a1, whf[kt][1], acc11, 0, 0, 0);
        }

        // ---- wait: in-feed ready (layer>0); throttle vs consumer (ring depth 4) ----
        if (tid == 0) {
            if (layer > 0) {
                int* fp = flags + (layer - 1)*8 + mg;
                while (__hip_atomic_load(fp, __ATOMIC_ACQUIRE, __HIP_MEMORY_SCOPE_AGENT) < 4*(t + 1))
                    __builtin_amdgcn_s_sleep(2);
            }
            if (layer < 2 && t >= 4) {
                int* fn = flags + (layer + 1)*8 + mg;
                while (__hip_atomic_load(fn, __ATOMIC_ACQUIRE, __HIP_MEMORY_SCOPE_AGENT) < 4*(t - 3))
                    __builtin_amdgcn_s_sleep(2);
            }
        }
        __syncthreads();

        if (layer > 0) {
            // stage h_{l-1}(t) -> Ain (swizzled)
            const uint4v* src = (const uint4v*)(hbuf + (((layer - 1)*8 + mg)*4 + (t & 3)) * 16384);
#pragma unroll
            for (int i = 0; i < 8; ++i) {
                int ci = i*256 + tid;
                int r  = ci >> 6;
                int cc = ci & 63;
                *(uint4v*)&Ain[r][((cc + r) & 63) * 8] = src[ci];
            }
            __syncthreads();
#pragma unroll
            for (int kt = 0; kt < 16; ++kt) {
                half8 a0 = *(const half8*)&Ain[c16]     [((kt*4 + q + c16)      & 63) * 8];
                half8 a1 = *(const half8*)&Ain[16 + c16][((kt*4 + q + 16 + c16) & 63) * 8];
                acc00 = __builtin_amdgcn_mfma_f32_16x16x32_f16(a0, wxf[kt][0], acc00, 0, 0, 0);
                acc01 = __builtin_amdgcn_mfma_f32_16x16x32_f16(a0, wxf[kt][1], acc01, 0, 0, 0);
                acc10 = __builtin_amdgcn_mfma_f32_16x16x32_f16(a1, wxf[kt][0], acc10, 0, 0, 0);
                acc11 = __builtin_amdgcn_mfma_f32_16x16x32_f16(a1, wxf[kt][1], acc11, 0, 0, 0);
            }
        } else {
            // x_t @ Wx0 (K=128)
#pragma unroll
            for (int kt = 0; kt < 4; ++kt) {
                half8 a0 = *(const half8*)&Ain[c16]     [((kt*4 + q + c16)      & 63) * 8];
                half8 a1 = *(const half8*)&Ain[16 + c16][((kt*4 + q + 16 + c16) & 63) * 8];
                acc00 = __builtin_amdgcn_mfma_f32_16x16x32_f16(a0, wxf[kt][0], acc00, 0, 0, 0);
                acc01 = __builtin_amdgcn_mfma_f32_16x16x32_f16(a0, wxf[kt][1], acc01, 0, 0, 0);
                acc10 = __builtin_amdgcn_mfma_f32_16x16x32_f16(a1, wxf[kt][0], acc10, 0, 0, 0);
                acc11 = __builtin_amdgcn_mfma_f32_16x16x32_f16(a1, wxf[kt][1], acc11, 0, 0, 0);
            }
        }

        // ---- epilogue: +bias, tanh, store fp16 tile to ring slot t&3 ----
        {
            _Float16* dst = hbuf + (slotBase + (t & 3)) * 16384;
#pragma unroll
            for (int r = 0; r < 4; ++r) {
                int row0 = q*4 + r;
                int row1 = 16 + row0;
                float z, e;
                z = acc00[r] + bv0; e = __expf(2.0f * z);
                dst[row0*UNIT + c0 + c16]      = (_Float16)(1.0f - 2.0f/(e + 1.0f));
                z = acc01[r] + bv1; e = __expf(2.0f * z);
                dst[row0*UNIT + c0 + 16 + c16] = (_Float16)(1.0f - 2.0f/(e + 1.0f));
                z = acc10[r] + bv0; e = __expf(2.0f * z);
                dst[row1*UNIT + c0 + c16]      = (_Float16)(1.0f - 2.0f/(e + 1.0f));
                z = acc11[r] + bv1; e = __expf(2.0f * z);
                dst[row1*UNIT + c0 + 16 + c16] = (_Float16)(1.0f - 2.0f/(e + 1.0f));
            }
        }
        __syncthreads();   // drains vmcnt: all strip stores visible before release
        if (tid == 0)
            __hip_atomic_fetch_add(flagOwn, 1, __ATOMIC_RELEASE, __HIP_MEMORY_SCOPE_AGENT);
    }
}

// ---------------------------------------------------------------------------
// logits = h2(T-1) @ fc_w + fc_b ; out = sigmoid(logits). One block per row.
__global__ void fc_kernel(const char* __restrict__ ws,
                          const float* __restrict__ fc_w,
                          const float* __restrict__ fc_b,
                          float* __restrict__ out)
{
    int row  = blockIdx.x;
    int lane = threadIdx.x;          // 64
    int m = row >> 5, lr = row & 31;
    const _Float16* h2 = (const _Float16*)(ws + HBUF_OFF)
                         + (((2*8 + m)*4 + 3) * 16384)   // slot 511&3 = 3
                         + lr * UNIT;
    half8 hv = *(const half8*)&h2[lane * 8];
    const float* w = fc_w + lane * 8;
    float s = 0.0f;
#pragma unroll
    for (int j = 0; j < 8; ++j) s += (float)hv[j] * w[j];
#pragma unroll
    for (int off = 32; off > 0; off >>= 1) s += __shfl_down(s, off);
    if (lane == 0) {
        float logit = s + fc_b[0];
        out[row] = 1.0f / (1.0f + __expf(-logit));
    }
}

// ---------------------------------------------------------------------------
extern "C" void kernel_launch(void* const* d_in, const int* in_sizes, int n_in,
                              void* d_out, int out_size, void* d_ws, size_t ws_size,
                              hipStream_t stream)
{
    const int*   tokens = (const int*)  d_in[0];
    const float* emb    = (const float*)d_in[1];
    const float* Wx0    = (const float*)d_in[2];
    const float* Wh0    = (const float*)d_in[3];
    const float* b0     = (const float*)d_in[4];
    const float* Wx1    = (const float*)d_in[5];
    const float* Wh1    = (const float*)d_in[6];
    const float* b1     = (const float*)d_in[7];
    const float* fcw    = (const float*)d_in[8];
    const float* fcb    = (const float*)d_in[9];
    char*  ws  = (char*)d_ws;
    float* out = (float*)d_out;

    // 1) zero flags + h ring buffers (ws is re-poisoned 0xAA before every launch)
    int n16 = (FLAGS_BYTES + HBUF_BYTES) / 16;
    zero_ws_kernel<<<(n16 + 255)/256, 256, 0, stream>>>((uint4v*)ws, n16);

    // 2) pack weights fp32 -> fp16 B-fragment layout
    pack_w_kernel<<<(EMBD*UNIT + 255)/256, 256, 0, stream>>>(Wx0, (_Float16*)(ws + PWX0_OFF), EMBD, UNIT);
    pack_w_kernel<<<(UNIT*UNIT + 255)/256, 256, 0, stream>>>(Wh0, (_Float16*)(ws + PWH0_OFF), UNIT, UNIT);
    pack_w_kernel<<<(UNIT*UNIT + 255)/256, 256, 0, stream>>>(Wx1, (_Float16*)(ws + PWX1_OFF), UNIT, UNIT);
    pack_w_kernel<<<(UNIT*UNIT + 255)/256, 256, 0, stream>>>(Wh1, (_Float16*)(ws + PWH1_OFF), UNIT, UNIT);

    // 3) pipelined recurrence: 96 blocks = 3 layers x 8 batch-groups x 4 N-strips
    rnn_main_kernel<<<96, 256, 0, stream>>>(tokens, emb, b0, b1, ws);

    // 4) final FC + sigmoid
    fc_kernel<<<256, 64, 0, stream>>>((const char*)ws, fcw, fcb, out);
}

// Round 2
// 4068.637 us; speedup vs baseline: 1.6127x; 1.6127x over previous
//
#include <hip/hip_runtime.h>

// ---------------------------------------------------------------------------
// 3-layer SimpleRNN, B=256 T=512 U=512 E=128, fp16 MFMA, pipelined across
// layers with flag-based producer/consumer sync.
//
// R2: sync rebuilt to be cache-maintenance-free.
//  - flags: relaxed agent-scope atomic RMW (poll = fetch_add 0) -> coherence
//    point, no buffer_inv/buffer_wbl2 per step.
//  - h-ring data: sc0 sc1 global loads/stores (bypass L1+L2) via batched
//    inline asm with one trailing s_waitcnt.
//  - epilogue stores coalesced through an 8KB LDS bounce.
//  - own 128-col chunk of h kept in LDS (24KB instead of 32KB staged/step).
// ---------------------------------------------------------------------------

#define BATCH 256
#define SEQ   512
#define EMBD  128
#define UNIT  512

typedef _Float16 half8 __attribute__((ext_vector_type(8)));
typedef _Float16 half4 __attribute__((ext_vector_type(4)));
typedef float    f32x4 __attribute__((ext_vector_type(4)));
typedef unsigned int uint4v __attribute__((ext_vector_type(4)));

// ws layout (bytes). Total ~4.63 MB.
#define FLAGS_BYTES 4096
#define HBUF_OFF    4096
#define HBUF_ELEMS  (3*8*4*32*512)          // [layer][mgroup][slot][32][512] f16
#define HBUF_BYTES  (HBUF_ELEMS*2)
#define PWX0_OFF    (HBUF_OFF + HBUF_BYTES)
#define PWH0_OFF    (PWX0_OFF + EMBD*UNIT*2)
#define PWX1_OFF    (PWH0_OFF + UNIT*UNIT*2)
#define PWH1_OFF    (PWX1_OFF + UNIT*UNIT*2)

// ---------------------------------------------------------------------------
__device__ __forceinline__ int flag_read(int* p) {
    // RMW poll: executes at the coherence point -> always fresh, no cache ops.
    return __hip_atomic_fetch_add(p, 0, __ATOMIC_RELAXED, __HIP_MEMORY_SCOPE_AGENT);
}
__device__ __forceinline__ void flag_add(int* p) {
    __hip_atomic_fetch_add(p, 1, __ATOMIC_RELAXED, __HIP_MEMORY_SCOPE_AGENT);
}

__device__ __forceinline__ void sc_load8(
    const uint4v* p0, const uint4v* p1, const uint4v* p2, const uint4v* p3,
    const uint4v* p4, const uint4v* p5, const uint4v* p6, const uint4v* p7,
    uint4v& r0, uint4v& r1, uint4v& r2, uint4v& r3,
    uint4v& r4, uint4v& r5, uint4v& r6, uint4v& r7)
{
    asm volatile(
        "global_load_dwordx4 %0, %8, off sc0 sc1\n\t"
        "global_load_dwordx4 %1, %9, off sc0 sc1\n\t"
        "global_load_dwordx4 %2, %10, off sc0 sc1\n\t"
        "global_load_dwordx4 %3, %11, off sc0 sc1\n\t"
        "global_load_dwordx4 %4, %12, off sc0 sc1\n\t"
        "global_load_dwordx4 %5, %13, off sc0 sc1\n\t"
        "global_load_dwordx4 %6, %14, off sc0 sc1\n\t"
        "global_load_dwordx4 %7, %15, off sc0 sc1\n\t"
        "s_waitcnt vmcnt(0)"
        : "=&v"(r0), "=&v"(r1), "=&v"(r2), "=&v"(r3),
          "=&v"(r4), "=&v"(r5), "=&v"(r6), "=&v"(r7)
        : "v"(p0), "v"(p1), "v"(p2), "v"(p3),
          "v"(p4), "v"(p5), "v"(p6), "v"(p7)
        : "memory");
}

__device__ __forceinline__ void sc_load6(
    const uint4v* p0, const uint4v* p1, const uint4v* p2,
    const uint4v* p3, const uint4v* p4, const uint4v* p5,
    uint4v& r0, uint4v& r1, uint4v& r2, uint4v& r3, uint4v& r4, uint4v& r5)
{
    asm volatile(
        "global_load_dwordx4 %0, %6, off sc0 sc1\n\t"
        "global_load_dwordx4 %1, %7, off sc0 sc1\n\t"
        "global_load_dwordx4 %2, %8, off sc0 sc1\n\t"
        "global_load_dwordx4 %3, %9, off sc0 sc1\n\t"
        "global_load_dwordx4 %4, %10, off sc0 sc1\n\t"
        "global_load_dwordx4 %5, %11, off sc0 sc1\n\t"
        "s_waitcnt vmcnt(0)"
        : "=&v"(r0), "=&v"(r1), "=&v"(r2), "=&v"(r3), "=&v"(r4), "=&v"(r5)
        : "v"(p0), "v"(p1), "v"(p2), "v"(p3), "v"(p4), "v"(p5)
        : "memory");
}

__device__ __forceinline__ void sc_store2(uint4v* p0, uint4v v0, uint4v* p1, uint4v v1)
{
    asm volatile(
        "global_store_dwordx4 %0, %2, off sc0 sc1\n\t"
        "global_store_dwordx4 %1, %3, off sc0 sc1\n\t"
        "s_waitcnt vmcnt(0)"
        :: "v"(p0), "v"(p1), "v"(v0), "v"(v1)
        : "memory");
}

// ---------------------------------------------------------------------------
__global__ void zero_ws_kernel(uint4v* __restrict__ p, int n16) {
    int i = blockIdx.x * 256 + threadIdx.x;
    uint4v z = {0u, 0u, 0u, 0u};
    if (i < n16) p[i] = z;
}

// Pack fp32 weight [K][N] into MFMA B-fragment order, fp16:
// dst[((nt*KT + kt)*64 + lane)*8 + j] = W[kt*32 + (lane>>4)*8 + j][nt*16 + (lane&15)]
__global__ void pack_w_kernel(const float* __restrict__ src, _Float16* __restrict__ dst,
                              int K, int N) {
    int idx = blockIdx.x * 256 + threadIdx.x;
    if (idx >= K * N) return;
    int j    = idx & 7;
    int lane = (idx >> 3) & 63;
    int rest = idx >> 9;
    int KT   = K >> 5;
    int kt   = rest % KT;
    int nt   = rest / KT;
    int k = kt*32 + (lane >> 4)*8 + j;
    int n = nt*16 + (lane & 15);
    dst[idx] = (_Float16)src[k * N + n];
}

// ---------------------------------------------------------------------------
__global__ __launch_bounds__(256, 1)
void rnn_main_kernel(const int*   __restrict__ tokens,
                     const float* __restrict__ emb,
                     const float* __restrict__ b0,
                     const float* __restrict__ b1,
                     char* ws)
{
    const int bid   = blockIdx.x;
    const int layer = bid >> 5;          // 0..2
    const int mg    = (bid >> 2) & 7;    // batch group (32 rows)
    const int ns    = bid & 3;           // N-strip (128 cols)
    const int tid   = threadIdx.x;
    const int wv    = tid >> 6;
    const int lane  = tid & 63;
    const int q     = lane >> 4;         // quad
    const int c16   = lane & 15;

    int* flags   = (int*)ws;
    int* flagOwn = flags + layer*8 + mg;

    _Float16* hbuf = (_Float16*)(ws + HBUF_OFF);
    const _Float16* pWh = (const _Float16*)(ws + (layer == 0 ? PWH0_OFF : PWH1_OFF));
    const _Float16* pWx = (const _Float16*)(ws + (layer == 0 ? PWX0_OFF : PWX1_OFF));
    const float* bias = (layer == 0) ? b0 : b1;

    const int c0  = ns*128 + wv*32;      // global col base of this wave
    const int nt0 = c0 >> 4;

    // LDS. Rows swizzled by 16B-chunk rotation (chunk' = (chunk+row)&63).
    __shared__ _Float16 Ah [32][512];    // h_l(t-1) A-tile
    __shared__ _Float16 Ain[32][512];    // input A-tile (x_t or h_{l-1}(t))
    __shared__ _Float16 Bounce[32][128]; // epilogue store-coalescing bounce

    // zero Ah: h(-1) = 0
    {
        uint4v z = {0u,0u,0u,0u};
#pragma unroll
        for (int i = 0; i < 8; ++i) ((uint4v*)Ah)[i*256 + tid] = z;
    }

    // ---- register-resident weights (B-fragments) ----
    half8 whf[16][2];
    half8 wxf[16][2];
#pragma unroll
    for (int kt = 0; kt < 16; ++kt)
#pragma unroll
        for (int n = 0; n < 2; ++n)
            whf[kt][n] = *(const half8*)&pWh[(((nt0 + n)*16 + kt)*64 + lane) * 8];
    if (layer == 0) {
#pragma unroll
        for (int kt = 0; kt < 4; ++kt)
#pragma unroll
            for (int n = 0; n < 2; ++n)
                wxf[kt][n] = *(const half8*)&pWx[(((nt0 + n)*4 + kt)*64 + lane) * 8];
    } else {
#pragma unroll
        for (int kt = 0; kt < 16; ++kt)
#pragma unroll
            for (int n = 0; n < 2; ++n)
                wxf[kt][n] = *(const half8*)&pWx[(((nt0 + n)*16 + kt)*64 + lane) * 8];
    }

    const float bv0 = bias[c0 + c16];
    const float bv1 = bias[c0 + 16 + c16];

    const int m0       = mg * 32;
    const int slotBase = (layer*8 + mg) * 4;

    // sibling strip ids (the 3 strips != ns, ascending)
    const int sA = (ns == 0) ? 1 : 0;
    const int sB = (ns <= 1) ? 2 : 1;
    const int sC = (ns <= 2) ? 3 : 2;

    for (int t = 0; t < SEQ; ++t) {
        // ================= input side (off the recurrence critical path) ====
        if (layer == 0) {
            // stage x_t = fp16(emb[tokens[:, t]]) -> Ain cols 0..127 (swizzled)
#pragma unroll
            for (int i = 0; i < 4; ++i) {
                int idx = i*256 + tid;           // 1024 float4 chunks (32 rows x 32)
                int r   = idx >> 5;
                int qq  = idx & 31;
                int tok = tokens[(m0 + r)*SEQ + t];
                float4 f = *((const float4*)(emb + (long)tok * EMBD) + qq);
                half4 h = { (_Float16)f.x, (_Float16)f.y, (_Float16)f.z, (_Float16)f.w };
                *(half4*)&Ain[r][((((qq >> 1) + r) & 63) * 8) + (qq & 1) * 4] = h;
            }
        } else {
            if (tid == 0) {
                int* fp = flags + (layer - 1)*8 + mg;
                while (flag_read(fp) < 4*(t + 1)) __builtin_amdgcn_s_sleep(2);
            }
            __syncthreads();   // (A) upstream slot t&3 ready
            const uint4v* sb = (const uint4v*)(hbuf + (((layer - 1)*8 + mg)*4 + (t & 3)) * 16384);
            uint4v rr[8];
            sc_load8(sb +        tid, sb +  256 + tid, sb +  512 + tid, sb +  768 + tid,
                     sb + 1024 + tid, sb + 1280 + tid, sb + 1536 + tid, sb + 1792 + tid,
                     rr[0], rr[1], rr[2], rr[3], rr[4], rr[5], rr[6], rr[7]);
#pragma unroll
            for (int i = 0; i < 8; ++i) {
                int ci = i*256 + tid;
                int r  = ci >> 6;
                int cc = ci & 63;
                *(uint4v*)&Ain[r][((cc + r) & 63) * 8] = rr[i];
            }
        }
        __syncthreads();       // (B) Ain ready

        f32x4 acc00 = {0,0,0,0}, acc01 = {0,0,0,0}, acc10 = {0,0,0,0}, acc11 = {0,0,0,0};

        // ---- Wx GEMM ----
        if (layer == 0) {
#pragma unroll
            for (int kt = 0; kt < 4; ++kt) {
                half8 a0 = *(const half8*)&Ain[c16]     [((kt*4 + q + c16)      & 63) * 8];
                half8 a1 = *(const half8*)&Ain[16 + c16][((kt*4 + q + 16 + c16) & 63) * 8];
                acc00 = __builtin_amdgcn_mfma_f32_16x16x32_f16(a0, wxf[kt][0], acc00, 0, 0, 0);
                acc01 = __builtin_amdgcn_mfma_f32_16x16x32_f16(a0, wxf[kt][1], acc01, 0, 0, 0);
                acc10 = __builtin_amdgcn_mfma_f32_16x16x32_f16(a1, wxf[kt][0], acc10, 0, 0, 0);
                acc11 = __builtin_amdgcn_mfma_f32_16x16x32_f16(a1, wxf[kt][1], acc11, 0, 0, 0);
            }
        } else {
#pragma unroll
            for (int kt = 0; kt < 16; ++kt) {
                half8 a0 = *(const half8*)&Ain[c16]     [((kt*4 + q + c16)      & 63) * 8];
                half8 a1 = *(const half8*)&Ain[16 + c16][((kt*4 + q + 16 + c16) & 63) * 8];
                acc00 = __builtin_amdgcn_mfma_f32_16x16x32_f16(a0, wxf[kt][0], acc00, 0, 0, 0);
                acc01 = __builtin_amdgcn_mfma_f32_16x16x32_f16(a0, wxf[kt][1], acc01, 0, 0, 0);
                acc10 = __builtin_amdgcn_mfma_f32_16x16x32_f16(a1, wxf[kt][0], acc10, 0, 0, 0);
                acc11 = __builtin_amdgcn_mfma_f32_16x16x32_f16(a1, wxf[kt][1], acc11, 0, 0, 0);
            }
        }

        // ================= recurrence critical path =========================
        if (tid == 0) {
            while (flag_read(flagOwn) < 4*t) __builtin_amdgcn_s_sleep(1);
            if (layer < 2 && t >= 4) {           // ring-overwrite throttle
                int* fn = flags + (layer + 1)*8 + mg;
                while (flag_read(fn) < 4*(t - 3)) __builtin_amdgcn_s_sleep(2);
            }
        }
        __syncthreads();       // (C) siblings' h(t-1) ready; slot t&3 free

        // stage the 3 sibling 128-col chunks of h(t-1) -> Ah (own chunk already in LDS)
        {
            const uint4v* tp = (const uint4v*)(hbuf + (slotBase + ((t + 3) & 3)) * 16384);
            int j0 = 2*tid, j1 = j0 + 1;
            int r0i = j0 >> 4, cl0 = j0 & 15;
            int r1i = j1 >> 4, cl1 = j1 & 15;
            int ccA0 = sA*16 + cl0, ccA1 = sA*16 + cl1;
            int ccB0 = sB*16 + cl0, ccB1 = sB*16 + cl1;
            int ccC0 = sC*16 + cl0, ccC1 = sC*16 + cl1;
            uint4v s0, s1, s2, s3, s4, s5;
            sc_load6(tp + r0i*64 + ccA0, tp + r1i*64 + ccA1,
                     tp + r0i*64 + ccB0, tp + r1i*64 + ccB1,
                     tp + r0i*64 + ccC0, tp + r1i*64 + ccC1,
                     s0, s1, s2, s3, s4, s5);
            *(uint4v*)&Ah[r0i][((ccA0 + r0i) & 63) * 8] = s0;
            *(uint4v*)&Ah[r1i][((ccA1 + r1i) & 63) * 8] = s1;
            *(uint4v*)&Ah[r0i][((ccB0 + r0i) & 63) * 8] = s2;
            *(uint4v*)&Ah[r1i][((ccB1 + r1i) & 63) * 8] = s3;
            *(uint4v*)&Ah[r0i][((ccC0 + r0i) & 63) * 8] = s4;
            *(uint4v*)&Ah[r1i][((ccC1 + r1i) & 63) * 8] = s5;
        }
        __syncthreads();       // (D) Ah ready

        // ---- Wh GEMM ----
#pragma unroll
        for (int kt = 0; kt < 16; ++kt) {
            half8 a0 = *(const half8*)&Ah[c16]     [((kt*4 + q + c16)      & 63) * 8];
            half8 a1 = *(const half8*)&Ah[16 + c16][((kt*4 + q + 16 + c16) & 63) * 8];
            acc00 = __builtin_amdgcn_mfma_f32_16x16x32_f16(a0, whf[kt][0], acc00, 0, 0, 0);
            acc01 = __builtin_amdgcn_mfma_f32_16x16x32_f16(a0, whf[kt][1], acc01, 0, 0, 0);
            acc10 = __builtin_amdgcn_mfma_f32_16x16x32_f16(a1, whf[kt][0], acc10, 0, 0, 0);
            acc11 = __builtin_amdgcn_mfma_f32_16x16x32_f16(a1, whf[kt][1], acc11, 0, 0, 0);
        }

        // ---- epilogue phase 1: tanh -> regs + Bounce (LDS) ----
        _Float16 hv[16];
        const int l0 = wv*32 + c16;
        const int l1 = l0 + 16;
#pragma unroll
        for (int r = 0; r < 4; ++r) {
            int row0 = q*4 + r;
            int row1 = 16 + row0;
            float z, e; _Float16 v;
            z = acc00[r] + bv0; e = __expf(2.0f*z); v = (_Float16)(1.0f - 2.0f/(e + 1.0f));
            hv[r*4 + 0] = v; Bounce[row0][l0] = v;
            z = acc01[r] + bv1; e = __expf(2.0f*z); v = (_Float16)(1.0f - 2.0f/(e + 1.0f));
            hv[r*4 + 1] = v; Bounce[row0][l1] = v;
            z = acc10[r] + bv0; e = __expf(2.0f*z); v = (_Float16)(1.0f - 2.0f/(e + 1.0f));
            hv[r*4 + 2] = v; Bounce[row1][l0] = v;
            z = acc11[r] + bv1; e = __expf(2.0f*z); v = (_Float16)(1.0f - 2.0f/(e + 1.0f));
            hv[r*4 + 3] = v; Bounce[row1][l1] = v;
        }
        __syncthreads();       // (E) all waves done reading Ah; Bounce complete

        // ---- epilogue phase 2: own chunk -> Ah(t); Bounce -> ring (coalesced sc) ----
        {
            int g0 = c0 + c16;
            int g1 = c0 + 16 + c16;
#pragma unroll
            for (int r = 0; r < 4; ++r) {
                int row0 = q*4 + r;
                int row1 = 16 + row0;
                Ah[row0][(((g0 >> 3) + row0) & 63)*8 + (g0 & 7)] = hv[r*4 + 0];
                Ah[row0][(((g1 >> 3) + row0) & 63)*8 + (g1 & 7)] = hv[r*4 + 1];
                Ah[row1][(((g0 >> 3) + row1) & 63)*8 + (g0 & 7)] = hv[r*4 + 2];
                Ah[row1][(((g1 >> 3) + row1) & 63)*8 + (g1 & 7)] = hv[r*4 + 3];
            }
            _Float16* tc = hbuf + (slotBase + (t & 3)) * 16384;
            int j0 = 2*tid, j1 = j0 + 1;
            uint4v v0 = ((const uint4v*)Bounce)[j0];
            uint4v v1 = ((const uint4v*)Bounce)[j1];
            uint4v* d0 = (uint4v*)(tc + (j0 >> 4)*512 + ns*128) + (j0 & 15);
            uint4v* d1 = (uint4v*)(tc + (j1 >> 4)*512 + ns*128) + (j1 & 15);
            sc_store2(d0, v0, d1, v1);
        }
        __syncthreads();       // (F) all lanes' sc-stores drained (in-asm vmcnt(0))
        if (tid == 0) flag_add(flagOwn);
    }
}

// ---------------------------------------------------------------------------
// logits = h2(T-1) @ fc_w + fc_b ; out = sigmoid(logits). One block per row.
__global__ void fc_kernel(const char* __restrict__ ws,
                          const float* __restrict__ fc_w,
                          const float* __restrict__ fc_b,
                          float* __restrict__ out)
{
    int row  = blockIdx.x;
    int lane = threadIdx.x;          // 64
    int m = row >> 5, lr = row & 31;
    const _Float16* h2 = (const _Float16*)(ws + HBUF_OFF)
                         + (((2*8 + m)*4 + 3) * 16384)   // slot 511&3 = 3
                         + lr * UNIT;
    half8 hv = *(const half8*)&h2[lane * 8];
    const float* w = fc_w + lane * 8;
    float s = 0.0f;
#pragma unroll
    for (int j = 0; j < 8; ++j) s += (float)hv[j] * w[j];
#pragma unroll
    for (int off = 32; off > 0; off >>= 1) s += __shfl_down(s, off);
    if (lane == 0) {
        float logit = s + fc_b[0];
        out[row] = 1.0f / (1.0f + __expf(-logit));
    }
}

// ---------------------------------------------------------------------------
extern "C" void kernel_launch(void* const* d_in, const int* in_sizes, int n_in,
                              void* d_out, int out_size, void* d_ws, size_t ws_size,
                              hipStream_t stream)
{
    const int*   tokens = (const int*)  d_in[0];
    const float* emb    = (const float*)d_in[1];
    const float* Wx0    = (const float*)d_in[2];
    const float* Wh0    = (const float*)d_in[3];
    const float* b0     = (const float*)d_in[4];
    const float* Wx1    = (const float*)d_in[5];
    const float* Wh1    = (const float*)d_in[6];
    const float* b1     = (const float*)d_in[7];
    const float* fcw    = (const float*)d_in[8];
    const float* fcb    = (const float*)d_in[9];
    char*  ws  = (char*)d_ws;
    float* out = (float*)d_out;

    // 1) zero flags + h ring buffers (plain stores; dispatch-end flush makes
    //    them visible to the sc0sc1/atomic accesses of the next kernel)
    int n16 = (FLAGS_BYTES + HBUF_BYTES) / 16;
    zero_ws_kernel<<<(n16 + 255)/256, 256, 0, stream>>>((uint4v*)ws, n16);

    // 2) pack weights fp32 -> fp16 B-fragment layout
    pack_w_kernel<<<(EMBD*UNIT + 255)/256, 256, 0, stream>>>(Wx0, (_Float16*)(ws + PWX0_OFF), EMBD, UNIT);
    pack_w_kernel<<<(UNIT*UNIT + 255)/256, 256, 0, stream>>>(Wh0, (_Float16*)(ws + PWH0_OFF), UNIT, UNIT);
    pack_w_kernel<<<(UNIT*UNIT + 255)/256, 256, 0, stream>>>(Wx1, (_Float16*)(ws + PWX1_OFF), UNIT, UNIT);
    pack_w_kernel<<<(UNIT*UNIT + 255)/256, 256, 0, stream>>>(Wh1, (_Float16*)(ws + PWH1_OFF), UNIT, UNIT);

    // 3) pipelined recurrence: 96 blocks = 3 layers x 8 batch-groups x 4 N-strips
    rnn_main_kernel<<<96, 256, 0, stream>>>(tokens, emb, b0, b1, ws);

    // 4) final FC + sigmoid
    fc_kernel<<<256, 64, 0, stream>>>((const char*)ws, fcw, fcb, out);
}